// Round 9
// baseline (254.263 us; speedup 1.0000x reference)
//
#include <hip/hip_runtime.h>

#define NROW 16384
#define DDIM 128
#define NITER (NROW / 64)

typedef _Float16 f16x8 __attribute__((ext_vector_type(8)));
typedef __fp16 fp16x2 __attribute__((ext_vector_type(2)));
typedef float f32x4 __attribute__((ext_vector_type(4)));

__device__ __forceinline__ unsigned short f2h(float x) {
  union { _Float16 f; unsigned short u; } cvt;
  cvt.f = (_Float16)x;  // RNE
  return cvt.u;
}

__device__ __forceinline__ unsigned pkrtz(float a, float b) {
  union { fp16x2 h; unsigned u; } cvt;
  cvt.h = __builtin_amdgcn_cvt_pkrtz(a, b);  // v_cvt_pkrtz_f16_f32
  return cvt.u;
}

// Raw barrier without the compiler's vmcnt(0) drain: lets prefetch loads
// stay in flight across the barrier (m97 barrier-drain workaround).
__device__ __forceinline__ void block_sync() {
  asm volatile("s_waitcnt lgkmcnt(0)" ::: "memory");  // ds reads+writes done
  __builtin_amdgcn_s_barrier();
  asm volatile("" ::: "memory");                      // no hoisting of reads
}

// ---------------- prep: ht[d][i] = fp16(h[i][d]) ----------------
__global__ __launch_bounds__(256) void prep_ht(const float* __restrict__ h,
                                               unsigned short* __restrict__ ht) {
  __shared__ unsigned short tile[DDIM][65];  // 65: 2-way-free transpose
  const int t = threadIdx.x;
  const int i0 = blockIdx.x * 64;
#pragma unroll
  for (int rep = 0; rep < 8; ++rep) {
    int idx = rep * 256 + t;          // 0..2047 float4s of a 64x128 tile
    int r = idx >> 5, c4 = idx & 31;
    const float4 v = *(const float4*)(h + (size_t)(i0 + r) * DDIM + c4 * 4);
    int c = c4 * 4;
    tile[c + 0][r] = f2h(v.x);
    tile[c + 1][r] = f2h(v.y);
    tile[c + 2][r] = f2h(v.z);
    tile[c + 3][r] = f2h(v.w);
  }
  __syncthreads();
#pragma unroll
  for (int rep = 0; rep < 4; ++rep) {
    int idx = rep * 256 + t;          // 0..1023 groups of 8
    int d = idx >> 3, io = (idx & 7) * 8;
    uint4 o;
    o.x = (unsigned)tile[d][io + 0] | ((unsigned)tile[d][io + 1] << 16);
    o.y = (unsigned)tile[d][io + 2] | ((unsigned)tile[d][io + 3] << 16);
    o.z = (unsigned)tile[d][io + 4] | ((unsigned)tile[d][io + 5] << 16);
    o.w = (unsigned)tile[d][io + 6] | ((unsigned)tile[d][io + 7] << 16);
    *(uint4*)(ht + (size_t)d * NROW + i0 + io) = o;
  }
}

// ---------------- fused: out = rownorm(exp(adj)) @ h ----------------
// R8 skeleton + cuts, re-phased as a software pipeline:
//   iter t: [ds_read+MFMA tile t from buf(t&1)]
//        || [exp/pack/LDS-write tile t+1 into buf((t+1)&1)]
//        || [global prefetch tile t+2]
//   -> lgkmcnt(0) -> raw barrier.
// Barrier-to-barrier path = max(phases), not sum. Dbuf invariant: reads of
// buf c (iter t) precede its overwrite (iter t+1) across one barrier.
__global__ __launch_bounds__(256, 2) void fused(const float* __restrict__ adj,
                                                const unsigned short* __restrict__ ht,
                                                float* __restrict__ out) {
  __shared__ __align__(16) char smem[40960];  // A: 2*4KB @0, BT: 2*16KB @8192
  const int t = threadIdx.x;
  const size_t m0 = (size_t)blockIdx.x * 32;

  // --- staging indices (pre-swizzled source chunk) ---
  const int srow = t >> 3;                         // 0..31
  const int chk = (t & 7) ^ (srow & 7);            // semantic 8-elem chunk
  const float* ap = adj + (m0 + srow) * (size_t)NROW + chk * 8;
  const unsigned short* hp = ht + (size_t)srow * NROW + chk * 8;

  // --- mfma indices ---
  const int l = t & 63, w = t >> 6;
  const int wr = w >> 1, wc = w & 1;
  const int lr = l & 15, kg = l >> 4;              // kg: k-group 0..3
  const int arow = wr * 16 + lr;                   // 0..31
  const int aoff0 = arow * 128 + (((kg    ) ^ (arow & 7)) << 4);
  const int aoff1 = arow * 128 + (((kg + 4) ^ (arow & 7)) << 4);
  const int d0 = wc * 64 + lr;                     // d&7 == lr&7 for all cf
  const int boff0 = d0 * 128 + (((kg    ) ^ (lr & 7)) << 4);
  const int boff1 = d0 * 128 + (((kg + 4) ^ (lr & 7)) << 4);

  f32x4 acc[4];
#pragma unroll
  for (int cf = 0; cf < 4; ++cf) acc[cf] = (f32x4){0.f, 0.f, 0.f, 0.f};
  f32x4 rsum = (f32x4){0.f, 0.f, 0.f, 0.f};  // rowsum via ones-column MFMA

  f16x8 ones;
#pragma unroll
  for (int e = 0; e < 8; ++e) ones[e] = (_Float16)1.0f;

  // ---- prologue ----
  // load tile 0
  float4 pa0 = *(const float4*)(ap);
  float4 pa1 = *(const float4*)(ap + 4);
  uint4 pb0 = *(const uint4*)(hp);
  uint4 pb1 = *(const uint4*)(hp + 32 * NROW);
  uint4 pb2 = *(const uint4*)(hp + 64 * NROW);
  uint4 pb3 = *(const uint4*)(hp + 96 * NROW);
  // stage tile 0 into buf0
  {
    uint4* bb = (uint4*)(smem + 8192);
    bb[t] = pb0; bb[t + 256] = pb1; bb[t + 512] = pb2; bb[t + 768] = pb3;
    uint4 aw;
    aw.x = pkrtz(__expf(pa0.x), __expf(pa0.y));
    aw.y = pkrtz(__expf(pa0.z), __expf(pa0.w));
    aw.z = pkrtz(__expf(pa1.x), __expf(pa1.y));
    aw.w = pkrtz(__expf(pa1.z), __expf(pa1.w));
    *(uint4*)(smem + t * 16) = aw;
  }
  // prefetch tile 1 (in flight across the raw barrier)
  if (NITER > 1) {
    const float* a = ap + 64;
    pa0 = *(const float4*)(a);
    pa1 = *(const float4*)(a + 4);
    const unsigned short* hb = hp + 64;
    pb0 = *(const uint4*)(hb);
    pb1 = *(const uint4*)(hb + 32 * NROW);
    pb2 = *(const uint4*)(hb + 64 * NROW);
    pb3 = *(const uint4*)(hb + 96 * NROW);
  }
  block_sync();

  // ---- main pipelined loop ----
  for (int it = 0; it < NITER; ++it) {
    const int cur = it & 1;
    const char* aB = smem + cur * 4096;
    const char* bB = smem + 8192 + cur * 16384;

    // (1) consume: issue all fragment reads for tile it
    f16x8 af0 = *(const f16x8*)(aB + aoff0);
    f16x8 af1 = *(const f16x8*)(aB + aoff1);
    f16x8 bf0[4], bf1[4];
#pragma unroll
    for (int cf = 0; cf < 4; ++cf) {
      bf0[cf] = *(const f16x8*)(bB + boff0 + cf * 2048);
      bf1[cf] = *(const f16x8*)(bB + boff1 + cf * 2048);
    }

    // (2) produce: tile it+1 -> other buffer (overlaps reads/MFMA)
    if (it + 1 < NITER) {
      uint4* bb = (uint4*)(smem + 8192 + (cur ^ 1) * 16384);
      bb[t] = pb0; bb[t + 256] = pb1; bb[t + 512] = pb2; bb[t + 768] = pb3;
      uint4 aw;
      aw.x = pkrtz(__expf(pa0.x), __expf(pa0.y));
      aw.y = pkrtz(__expf(pa0.z), __expf(pa0.w));
      aw.z = pkrtz(__expf(pa1.x), __expf(pa1.y));
      aw.w = pkrtz(__expf(pa1.z), __expf(pa1.w));
      *(uint4*)(smem + (cur ^ 1) * 4096 + t * 16) = aw;

      // (3) prefetch tile it+2
      if (it + 2 < NITER) {
        const float* a = ap + (it + 2) * 64;
        pa0 = *(const float4*)(a);
        pa1 = *(const float4*)(a + 4);
        const unsigned short* hb = hp + (it + 2) * 64;
        pb0 = *(const uint4*)(hb);
        pb1 = *(const uint4*)(hb + 32 * NROW);
        pb2 = *(const uint4*)(hb + 64 * NROW);
        pb3 = *(const uint4*)(hb + 96 * NROW);
      }
    }

    // (4) MFMA cluster (rowsum folded in via ones-column)
    __builtin_amdgcn_s_setprio(1);
    rsum = __builtin_amdgcn_mfma_f32_16x16x32_f16(af0, ones, rsum, 0, 0, 0);
#pragma unroll
    for (int cf = 0; cf < 4; ++cf)
      acc[cf] = __builtin_amdgcn_mfma_f32_16x16x32_f16(af0, bf0[cf], acc[cf], 0, 0, 0);
    rsum = __builtin_amdgcn_mfma_f32_16x16x32_f16(af1, ones, rsum, 0, 0, 0);
#pragma unroll
    for (int cf = 0; cf < 4; ++cf)
      acc[cf] = __builtin_amdgcn_mfma_f32_16x16x32_f16(af1, bf1[cf], acc[cf], 0, 0, 0);
    __builtin_amdgcn_s_setprio(0);

    // (5) rendezvous: all ds ops drained; global prefetch stays in flight
    block_sync();
  }

  // epilogue: D[(kg*4+r)][lr]; rsum[r] holds this lane's row's sum
#pragma unroll
  for (int r = 0; r < 4; ++r) {
    const int row_l = wr * 16 + kg * 4 + r;
    const float inv = 1.0f / rsum[r];
    float* orow = out + (m0 + row_l) * (size_t)DDIM + wc * 64 + lr;
#pragma unroll
    for (int cf = 0; cf < 4; ++cf) {
      orow[cf * 16] = acc[cf][r] * inv;
    }
  }
}

extern "C" void kernel_launch(void* const* d_in, const int* in_sizes, int n_in,
                              void* d_out, int out_size, void* d_ws, size_t ws_size,
                              hipStream_t stream) {
  (void)in_sizes; (void)n_in; (void)out_size; (void)ws_size;
  const float* h   = (const float*)d_in[0];
  const float* adj = (const float*)d_in[1];
  float* out = (float*)d_out;
  unsigned short* ht = (unsigned short*)d_ws;  // 128*16384 fp16 = 4 MB

  prep_ht<<<dim3(NROW / 64), dim3(256), 0, stream>>>(h, ht);
  fused<<<dim3(NROW / 32), dim3(256), 0, stream>>>(adj, ht, out);
}

// Round 10
// 248.518 us; speedup vs baseline: 1.0231x; 1.0231x over previous
//
#include <hip/hip_runtime.h>

#define NROW 16384
#define DDIM 128

typedef _Float16 f16x8 __attribute__((ext_vector_type(8)));
typedef __fp16 fp16x2 __attribute__((ext_vector_type(2)));
typedef float f32x4 __attribute__((ext_vector_type(4)));

__device__ __forceinline__ unsigned short f2h(float x) {
  union { _Float16 f; unsigned short u; } cvt;
  cvt.f = (_Float16)x;  // RNE
  return cvt.u;
}

__device__ __forceinline__ unsigned pkrtz(float a, float b) {
  union { fp16x2 h; unsigned u; } cvt;
  cvt.h = __builtin_amdgcn_cvt_pkrtz(a, b);  // v_cvt_pkrtz_f16_f32
  return cvt.u;
}

// Raw barrier without the compiler's vmcnt(0) drain: lets prefetch loads
// stay in flight across the barrier (m97 barrier-drain workaround).
__device__ __forceinline__ void block_sync() {
  asm volatile("s_waitcnt lgkmcnt(0)" ::: "memory");  // ds_writes done
  __builtin_amdgcn_s_barrier();
  asm volatile("" ::: "memory");                      // no hoisting of reads
}

// ---------------- prep: ht[d][i] = fp16(h[i][d]) ----------------
__global__ __launch_bounds__(256) void prep_ht(const float* __restrict__ h,
                                               unsigned short* __restrict__ ht) {
  __shared__ unsigned short tile[DDIM][65];  // 65: 2-way-free transpose
  const int t = threadIdx.x;
  const int i0 = blockIdx.x * 64;
#pragma unroll
  for (int rep = 0; rep < 8; ++rep) {
    int idx = rep * 256 + t;          // 0..2047 float4s of a 64x128 tile
    int r = idx >> 5, c4 = idx & 31;
    const float4 v = *(const float4*)(h + (size_t)(i0 + r) * DDIM + c4 * 4);
    int c = c4 * 4;
    tile[c + 0][r] = f2h(v.x);
    tile[c + 1][r] = f2h(v.y);
    tile[c + 2][r] = f2h(v.z);
    tile[c + 3][r] = f2h(v.w);
  }
  __syncthreads();
#pragma unroll
  for (int rep = 0; rep < 4; ++rep) {
    int idx = rep * 256 + t;          // 0..1023 groups of 8
    int d = idx >> 3, io = (idx & 7) * 8;
    uint4 o;
    o.x = (unsigned)tile[d][io + 0] | ((unsigned)tile[d][io + 1] << 16);
    o.y = (unsigned)tile[d][io + 2] | ((unsigned)tile[d][io + 3] << 16);
    o.z = (unsigned)tile[d][io + 4] | ((unsigned)tile[d][io + 5] << 16);
    o.w = (unsigned)tile[d][io + 6] | ((unsigned)tile[d][io + 7] << 16);
    *(uint4*)(ht + (size_t)d * NROW + i0 + io) = o;
  }
}

// ---------------- fused: out = rownorm(exp(adj)) @ h ----------------
// R8 skeleton + cuts (proven best, 246.8 us). R10 single change: bijective
// XCD-chunked block swizzle. Dispatch round-robins blocks over 8 XCDs; with
// swz = (bid&7)*64 + (bid>>3), XCD x owns 64 CONTIGUOUS 32-row stripes
// (one contiguous 128 MB adj range -> DRAM row/channel locality) and its
// 64 co-resident blocks share the same ht k-window in its private L2.
__global__ __launch_bounds__(256, 2) void fused(const float* __restrict__ adj,
                                                const unsigned short* __restrict__ ht,
                                                float* __restrict__ out) {
  __shared__ __align__(16) char smem[40960];  // A: 2*4KB @0, BT: 2*16KB @8192
  const int t = threadIdx.x;
  const int bid = blockIdx.x;
  const int swz = (bid & 7) * 64 + (bid >> 3);   // XCD-chunked, bijective (512%8==0)
  const size_t m0 = (size_t)swz * 32;

  // --- staging indices (pre-swizzled source chunk) ---
  const int srow = t >> 3;                         // 0..31
  const int chk = (t & 7) ^ (srow & 7);            // semantic 8-elem chunk
  const float* ap = adj + (m0 + srow) * (size_t)NROW + chk * 8;
  const unsigned short* hp = ht + (size_t)srow * NROW + chk * 8;

  // --- mfma indices ---
  const int l = t & 63, w = t >> 6;
  const int wr = w >> 1, wc = w & 1;
  const int lr = l & 15, kg = l >> 4;              // kg: k-group 0..3
  const int arow = wr * 16 + lr;                   // 0..31
  const int aoff0 = arow * 128 + (((kg    ) ^ (arow & 7)) << 4);
  const int aoff1 = arow * 128 + (((kg + 4) ^ (arow & 7)) << 4);
  const int d0 = wc * 64 + lr;                     // d&7 == lr&7 for all cf
  const int boff0 = d0 * 128 + (((kg    ) ^ (lr & 7)) << 4);
  const int boff1 = d0 * 128 + (((kg + 4) ^ (lr & 7)) << 4);

  f32x4 acc[4];
#pragma unroll
  for (int cf = 0; cf < 4; ++cf) acc[cf] = (f32x4){0.f, 0.f, 0.f, 0.f};
  f32x4 rsum = (f32x4){0.f, 0.f, 0.f, 0.f};  // rowsum via ones-column MFMA

  f16x8 ones;
#pragma unroll
  for (int e = 0; e < 8; ++e) ones[e] = (_Float16)1.0f;

  // prefetch tile 0
  float4 pa0 = *(const float4*)(ap);
  float4 pa1 = *(const float4*)(ap + 4);
  uint4 pb0 = *(const uint4*)(hp);
  uint4 pb1 = *(const uint4*)(hp + 32 * NROW);
  uint4 pb2 = *(const uint4*)(hp + 64 * NROW);
  uint4 pb3 = *(const uint4*)(hp + 96 * NROW);

  for (int it = 0; it < NROW / 64; ++it) {
    const int cur = it & 1;

    // 1. B LDS writes first (independent of exp -> overlaps VALU chain)
    uint4* bb = (uint4*)(smem + 8192 + cur * 16384);
    bb[t] = pb0; bb[t + 256] = pb1; bb[t + 512] = pb2; bb[t + 768] = pb3;

    // 2. issue B prefetch for t+1 (regs free after step 1)
    const float4 a0 = pa0, a1 = pa1;
    if (it + 1 < NROW / 64) {
      const unsigned short* hb = hp + (it + 1) * 64;
      pb0 = *(const uint4*)(hb);
      pb1 = *(const uint4*)(hb + 32 * NROW);
      pb2 = *(const uint4*)(hb + 64 * NROW);
      pb3 = *(const uint4*)(hb + 96 * NROW);
    }

    // 3. exp + pkrtz pack
    uint4 aw;
    aw.x = pkrtz(__expf(a0.x), __expf(a0.y));
    aw.y = pkrtz(__expf(a0.z), __expf(a0.w));
    aw.z = pkrtz(__expf(a1.x), __expf(a1.y));
    aw.w = pkrtz(__expf(a1.z), __expf(a1.w));

    // 4. A LDS write + A prefetch
    *(uint4*)(smem + cur * 4096 + t * 16) = aw;
    if (it + 1 < NROW / 64) {
      const float* a = ap + (it + 1) * 64;
      pa0 = *(const float4*)(a);
      pa1 = *(const float4*)(a + 4);
    }

    // 5. barrier (LDS visible; global prefetch stays in flight)
    block_sync();

    // 6. fragments + MFMA (rowsum folded in via ones-column)
    const char* aB = smem + cur * 4096;
    const char* bB = smem + 8192 + cur * 16384;
    __builtin_amdgcn_s_setprio(1);
    f16x8 af0 = *(const f16x8*)(aB + aoff0);
    f16x8 af1 = *(const f16x8*)(aB + aoff1);
    rsum = __builtin_amdgcn_mfma_f32_16x16x32_f16(af0, ones, rsum, 0, 0, 0);
#pragma unroll
    for (int cf = 0; cf < 4; ++cf) {
      f16x8 bf0 = *(const f16x8*)(bB + boff0 + cf * 2048);
      acc[cf] = __builtin_amdgcn_mfma_f32_16x16x32_f16(af0, bf0, acc[cf], 0, 0, 0);
    }
    rsum = __builtin_amdgcn_mfma_f32_16x16x32_f16(af1, ones, rsum, 0, 0, 0);
#pragma unroll
    for (int cf = 0; cf < 4; ++cf) {
      f16x8 bf1 = *(const f16x8*)(bB + boff1 + cf * 2048);
      acc[cf] = __builtin_amdgcn_mfma_f32_16x16x32_f16(af1, bf1, acc[cf], 0, 0, 0);
    }
    __builtin_amdgcn_s_setprio(0);
  }

  // epilogue: D[(kg*4+r)][lr]; rsum[r] holds this lane's row's sum
#pragma unroll
  for (int r = 0; r < 4; ++r) {
    const int row_l = wr * 16 + kg * 4 + r;
    const float inv = 1.0f / rsum[r];
    float* orow = out + (m0 + row_l) * (size_t)DDIM + wc * 64 + lr;
#pragma unroll
    for (int cf = 0; cf < 4; ++cf) {
      orow[cf * 16] = acc[cf][r] * inv;
    }
  }
}

extern "C" void kernel_launch(void* const* d_in, const int* in_sizes, int n_in,
                              void* d_out, int out_size, void* d_ws, size_t ws_size,
                              hipStream_t stream) {
  (void)in_sizes; (void)n_in; (void)out_size; (void)ws_size;
  const float* h   = (const float*)d_in[0];
  const float* adj = (const float*)d_in[1];
  float* out = (float*)d_out;
  unsigned short* ht = (unsigned short*)d_ws;  // 128*16384 fp16 = 4 MB

  prep_ht<<<dim3(NROW / 64), dim3(256), 0, stream>>>(h, ht);
  fused<<<dim3(NROW / 32), dim3(256), 0, stream>>>(adj, ht, out);
}